// Round 6
// baseline (41.908 us; speedup 1.0000x reference)
//
#include <hip/hip_runtime.h>

// GAT block, B=8, N=2048, F=64.
// out = softmax(mask_adj(relu(s1_i+s2_j+ab1))) @ h1  +  h2
//   h1 = x@W1^T + b1 ; h2 = x@W2^T + b2 (identity-mask layer is exactly h2)
// e = relu(...) in [0,~5] => exp safe, no max subtraction needed.
// k_attn R6: fully decoupled waves — each wave owns 16 rows x full j, private
// double-buffered hl + adj ring; ZERO barriers; all deps register-visible.

#define DEVI __device__ __forceinline__

typedef __attribute__((ext_vector_type(8))) short short8;
typedef __attribute__((ext_vector_type(4))) float floatx4;

DEVI unsigned short f2bf(float x) {
    unsigned u = __builtin_bit_cast(unsigned, x);
    unsigned r = u + 0x7FFFu + ((u >> 16) & 1u);
    return (unsigned short)(r >> 16);
}

DEVI short8 pack8(const float* v) {
    short8 r;
#pragma unroll
    for (int i = 0; i < 8; ++i) r[i] = (short)f2bf(v[i]);
    return r;
}

DEVI unsigned cvt_pk_bf16(float lo, float hi) {
    unsigned r;
    asm("v_cvt_pk_bf16_f32 %0, %1, %2" : "=v"(r) : "v"(lo), "v"(hi));
    return r;
}

// ---------------- Kernel 1: h1 (transposed, bf16), t1 = s1+ab1, s2 ----------
__global__ __launch_bounds__(256) void k_prep(
    const float* __restrict__ x, const float* __restrict__ W1,
    const float* __restrict__ b1, const float* __restrict__ a1,
    const float* __restrict__ ab1,
    unsigned short* __restrict__ hT1,   // [8][64][2048] bf16
    float* __restrict__ t1,             // [8*2048]
    float* __restrict__ s2a)            // [8*2048]
{
    __shared__ __align__(16) unsigned short hstage[64][72];
    const int tid = threadIdx.x;
    const int w = tid >> 6, lane = tid & 63;
    const int g = lane >> 4, r15 = lane & 15;
    const int blockRow = blockIdx.x * 64;
    const int rowbase = blockRow + w * 16;

    float xa[8], xb[8];
    const float* xrow = x + (long)(rowbase + r15) * 64;
#pragma unroll
    for (int e = 0; e < 8; ++e) { xa[e] = xrow[g * 8 + e]; xb[e] = xrow[32 + g * 8 + e]; }
    short8 A0 = pack8(xa), A1 = pack8(xb);

    floatx4 acc[4];
#pragma unroll
    for (int nt = 0; nt < 4; ++nt) {
        float wa[8], wb[8];
        const float* wrow = W1 + (nt * 16 + r15) * 64;
#pragma unroll
        for (int e = 0; e < 8; ++e) { wa[e] = wrow[g * 8 + e]; wb[e] = wrow[32 + g * 8 + e]; }
        short8 B0 = pack8(wa), B1 = pack8(wb);
        floatx4 c = {0.f, 0.f, 0.f, 0.f};
        c = __builtin_amdgcn_mfma_f32_16x16x32_bf16(A0, B0, c, 0, 0, 0);
        c = __builtin_amdgcn_mfma_f32_16x16x32_bf16(A1, B1, c, 0, 0, 0);
        float bias = b1[nt * 16 + r15];
#pragma unroll
        for (int q = 0; q < 4; ++q) c[q] += bias;
        acc[nt] = c;
    }

    float a1lo[4], a1hi[4];
#pragma unroll
    for (int nt = 0; nt < 4; ++nt) {
        a1lo[nt] = a1[nt * 16 + r15];
        a1hi[nt] = a1[64 + nt * 16 + r15];
    }
    float s1q[4], s2q[4];
#pragma unroll
    for (int q = 0; q < 4; ++q) {
        float s1 = 0.f, s2 = 0.f;
#pragma unroll
        for (int nt = 0; nt < 4; ++nt) { s1 += acc[nt][q] * a1lo[nt]; s2 += acc[nt][q] * a1hi[nt]; }
#pragma unroll
        for (int m = 1; m < 16; m <<= 1) { s1 += __shfl_xor(s1, m); s2 += __shfl_xor(s2, m); }
        s1q[q] = s1; s2q[q] = s2;
    }
    if (r15 == 0) {
        float abv = ab1[0];
#pragma unroll
        for (int q = 0; q < 4; ++q) {
            t1[rowbase + 4 * g + q] = s1q[q] + abv;
            s2a[rowbase + 4 * g + q] = s2q[q];
        }
    }

#pragma unroll
    for (int nt = 0; nt < 4; ++nt)
#pragma unroll
        for (int q = 0; q < 4; ++q)
            hstage[nt * 16 + r15][w * 16 + 4 * g + q] = f2bf(acc[nt][q]);
    __syncthreads();
    {
        const int o = tid >> 2, seg = (tid & 3) * 16;
        const int bb = blockRow >> 11;
        const int ib = blockRow & 2047;
        unsigned short* dst = hT1 + ((long)(bb * 64 + o) * 2048) + ib + seg;
        uint4 v0 = *(const uint4*)&hstage[o][seg];
        uint4 v1 = *(const uint4*)&hstage[o][seg + 8];
        *(uint4*)dst = v0;
        *(uint4*)(dst + 8) = v1;
    }
}

// ---------------- Kernel 2: masked softmax @ h1 + h2 ------------------------
// grid 256: bb = blockIdx&7 (XCD-local batch), i-tile = blockIdx>>3.
// block 256 = 4 fully independent waves, each: 16 rows x full j (32 chunks).
// No barriers anywhere; per-wave hl double-buffer (write-swizzled), adj ring-3.
__global__ __launch_bounds__(256, 1) void k_attn(
    const float* __restrict__ x, const int* __restrict__ adj,
    const float* __restrict__ W2, const float* __restrict__ b2,
    const unsigned short* __restrict__ hT1,
    const float* __restrict__ t1, const float* __restrict__ s2a,
    float* __restrict__ out)
{
    __shared__ __align__(16) unsigned short hl[4][8192];     // per-wave 2 bufs x [64][64]
    __shared__ __align__(16) unsigned short plds[4][16][72]; // per-wave P tile

    const int tid = threadIdx.x;
    const int w = tid >> 6, lane = tid & 63;
    const int g = lane >> 4, r15 = lane & 15;
    const int bb = blockIdx.x & 7;
    const int it = blockIdx.x >> 3;
    const int rowbase = it * 64 + w * 16;

    // hT staging lane roles (linear global read, swizzled LDS write)
    const int fr8 = lane >> 3;                 // f-subrow 0..7
    const int fsl = (lane & 7) ^ (fr8 & 7);    // swizzled 16B slot
    // b-frag read slots (undo swizzle): row&7 == r15&7
    const int bs0 = g ^ (r15 & 7);
    const int bs1 = (4 + g) ^ (r15 & 7);

    unsigned short* hlw = &hl[4][0] - 8192 * (4 - w);   // == &hl[w][0]
    unsigned short* pw = &plds[w][0][0];

    float tr4[4];
#pragma unroll
    for (int rr = 0; rr < 4; ++rr) tr4[rr] = t1[bb * 2048 + rowbase + rr * 4 + g];

    floatx4 acc[4];
#pragma unroll
    for (int nt = 0; nt < 4; ++nt) acc[nt] = (floatx4){0.f, 0.f, 0.f, 0.f};
    floatx4 acc5 = {0.f, 0.f, 0.f, 0.f};   // row-sums of P (denominator)

    short8 ones;
#pragma unroll
    for (int i = 0; i < 8; ++i) ones[i] = (short)0x3F80;   // bf16 1.0

    const int4* adjq = (const int4*)(adj + (long)(bb * 2048 + rowbase + g) * 2048) + r15;
    const float4* s2q4 = (const float4*)(s2a + (long)bb * 2048) + r15;
    const unsigned short* hTln = hT1 + (long)(bb * 64 + fr8) * 2048 + (lane & 7) * 8;

    int4 adjR[4][4];      // [slot][rr]
    float4 s2R[4];
    uint4 hrg[2][8];      // [chunk parity][k]

#define ADJ(c) do {                                                            \
        s2R[(c) & 3] = s2q4[(c) * 16];                                         \
        _Pragma("unroll")                                                      \
        for (int rr_ = 0; rr_ < 4; ++rr_)                                      \
            adjR[(c) & 3][rr_] = adjq[rr_ * 2048 + (c) * 16];                  \
    } while (0)

#define HTLOAD(c) do {                                                         \
        const unsigned short* s_ = hTln + (c) * 64;                            \
        _Pragma("unroll")                                                      \
        for (int k_ = 0; k_ < 8; ++k_)                                         \
            hrg[(c) & 1][k_] = *(const uint4*)(s_ + (long)k_ * 16384);         \
    } while (0)

#define HTSTORE(c) do {                                                        \
        _Pragma("unroll")                                                      \
        for (int k_ = 0; k_ < 8; ++k_)                                         \
            *(uint4*)&hlw[((c) & 1) * 4096 + (k_ * 8 + fr8) * 64 + fsl * 8]    \
                = hrg[(c) & 1][k_];                                            \
    } while (0)

#define COMPUTE(C) do {                                                        \
        const float4 s2v_ = s2R[(C) & 3];                                      \
        _Pragma("unroll")                                                      \
        for (int rr_ = 0; rr_ < 4; ++rr_) {                                    \
            float z0 = fmaxf(tr4[rr_] + s2v_.x, 0.f);                          \
            float z1 = fmaxf(tr4[rr_] + s2v_.y, 0.f);                          \
            float z2 = fmaxf(tr4[rr_] + s2v_.z, 0.f);                          \
            float z3 = fmaxf(tr4[rr_] + s2v_.w, 0.f);                          \
            float p0 = adjR[(C) & 3][rr_].x > 0 ? __expf(z0) : 0.f;            \
            float p1 = adjR[(C) & 3][rr_].y > 0 ? __expf(z1) : 0.f;            \
            float p2 = adjR[(C) & 3][rr_].z > 0 ? __expf(z2) : 0.f;            \
            float p3 = adjR[(C) & 3][rr_].w > 0 ? __expf(z3) : 0.f;            \
            uint2 u;                                                           \
            u.x = cvt_pk_bf16(p0, p1);                                         \
            u.y = cvt_pk_bf16(p2, p3);                                         \
            *(uint2*)&pw[(rr_ * 4 + g) * 72 + r15 * 4] = u;                    \
        }                                                                      \
        short8 a0 = *(const short8*)&pw[r15 * 72 + g * 8];                     \
        short8 a1 = *(const short8*)&pw[r15 * 72 + 32 + g * 8];                \
        const int bufo_ = ((C) & 1) * 4096;                                    \
        _Pragma("unroll")                                                      \
        for (int nt_ = 0; nt_ < 4; ++nt_) {                                    \
            short8 b0 = *(const short8*)&hlw[bufo_ + (nt_ * 16 + r15) * 64 + bs0 * 8]; \
            short8 b1 = *(const short8*)&hlw[bufo_ + (nt_ * 16 + r15) * 64 + bs1 * 8]; \
            acc[nt_] = __builtin_amdgcn_mfma_f32_16x16x32_bf16(a0, b0, acc[nt_], 0, 0, 0); \
            acc[nt_] = __builtin_amdgcn_mfma_f32_16x16x32_bf16(a1, b1, acc[nt_], 0, 0, 0); \
        }                                                                      \
        acc5 = __builtin_amdgcn_mfma_f32_16x16x32_bf16(a0, ones, acc5, 0, 0, 0); \
        acc5 = __builtin_amdgcn_mfma_f32_16x16x32_bf16(a1, ones, acc5, 0, 0, 0); \
    } while (0)

    // prologue: adj 3 deep, hT chunk 0 staged, chunk 1 in regs
    ADJ(0); ADJ(1); ADJ(2);
    HTLOAD(0);
    HTSTORE(0);
    HTLOAD(1);

#pragma unroll
    for (int C = 0; C < 32; ++C) {
        if (C + 2 <= 31) HTLOAD(C + 2);     // -> hrg[C&1] (freed: its chunk is in hl)
        if (C + 3 <= 31) ADJ(C + 3);        // -> slot (C+3)&3 (freed by compute C-1)
        if (C + 1 <= 31) HTSTORE(C + 1);    // hl[(C+1)&1] <- hrg[(C+1)&1]
        COMPUTE(C);                          // reads hl[C&1], adjR[C&3]
    }

#undef COMPUTE
#undef HTSTORE
#undef HTLOAD
#undef ADJ

    // ---- per-wave epilogue: normalize + h2 + store (no cross-wave traffic) ----
    float linv[4];
#pragma unroll
    for (int q = 0; q < 4; ++q) linv[q] = 1.0f / acc5[q];

    float xa[8], xb[8];
    const float* xrow = x + ((long)(bb * 2048 + rowbase + r15)) * 64;
#pragma unroll
    for (int e = 0; e < 8; ++e) { xa[e] = xrow[g * 8 + e]; xb[e] = xrow[32 + g * 8 + e]; }
    short8 A0 = pack8(xa), A1 = pack8(xb);
#pragma unroll
    for (int nt = 0; nt < 4; ++nt) {
        float wa[8], wb[8];
        const float* wrow2 = W2 + (nt * 16 + r15) * 64;
#pragma unroll
        for (int e = 0; e < 8; ++e) { wa[e] = wrow2[g * 8 + e]; wb[e] = wrow2[32 + g * 8 + e]; }
        short8 B0 = pack8(wa), B1 = pack8(wb);
        floatx4 c = {0.f, 0.f, 0.f, 0.f};
        c = __builtin_amdgcn_mfma_f32_16x16x32_bf16(A0, B0, c, 0, 0, 0);
        c = __builtin_amdgcn_mfma_f32_16x16x32_bf16(A1, B1, c, 0, 0, 0);
        float bias = b2[nt * 16 + r15];
#pragma unroll
        for (int q = 0; q < 4; ++q) {
            float val = acc[nt][q] * linv[q] + c[q] + bias;
            out[((long)(bb * 2048 + rowbase + 4 * g + q)) * 64 + nt * 16 + r15] = val;
        }
    }
}

extern "C" void kernel_launch(void* const* d_in, const int* in_sizes, int n_in,
                              void* d_out, int out_size, void* d_ws, size_t ws_size,
                              hipStream_t stream) {
    const float* x   = (const float*)d_in[0];
    const int*   adj = (const int*)d_in[1];
    // d_in[2] identity: unused (mask == I exactly -> layer2 == h2)
    const float* W1  = (const float*)d_in[3];
    const float* b1  = (const float*)d_in[4];
    const float* a1  = (const float*)d_in[5];
    const float* ab1 = (const float*)d_in[6];
    const float* W2  = (const float*)d_in[7];
    const float* b2  = (const float*)d_in[8];
    // d_in[9] a2, d_in[10] ab2: unused

    unsigned short* hT1 = (unsigned short*)d_ws;                 // 2 MB
    float* t1  = (float*)((char*)d_ws + (size_t)8 * 64 * 2048 * 2);
    float* s2a = t1 + 8 * 2048;

    k_prep<<<256, 256, 0, stream>>>(x, W1, b1, a1, ab1, hT1, t1, s2a);
    k_attn<<<256, 256, 0, stream>>>(x, adj, W2, b2, hT1, t1, s2a, (float*)d_out);
}

// Round 8
// 39.568 us; speedup vs baseline: 1.0591x; 1.0591x over previous
//
#include <hip/hip_runtime.h>

// GAT block, B=8, N=2048, F=64.
// out = softmax(mask_adj(relu(s1_i+s2_j+ab1))) @ h1  +  h2
//   h1 = x@W1^T + b1 ; h2 = x@W2^T + b2 (identity-mask layer is exactly h2)
// p_ij = adj ? exp(relu(t_i+s2_j)) : 0 = adj ? max(exp(t_i)*exp(s2_j), 1) : 0
// k_attn R8: R7 structure (16 waves = 4 row-groups x 4 j-teams, 4 waves/SIMD),
// with the adjR ring WAR hazard fixed: ADJ(C+2) issued AFTER COMPUTE(C).

#define DEVI __device__ __forceinline__

typedef __attribute__((ext_vector_type(8))) short short8;
typedef __attribute__((ext_vector_type(4))) float floatx4;

DEVI unsigned short f2bf(float x) {
    unsigned u = __builtin_bit_cast(unsigned, x);
    unsigned r = u + 0x7FFFu + ((u >> 16) & 1u);
    return (unsigned short)(r >> 16);
}

DEVI short8 pack8(const float* v) {
    short8 r;
#pragma unroll
    for (int i = 0; i < 8; ++i) r[i] = (short)f2bf(v[i]);
    return r;
}

DEVI unsigned cvt_pk_bf16(float lo, float hi) {
    unsigned r;
    asm("v_cvt_pk_bf16_f32 %0, %1, %2" : "=v"(r) : "v"(lo), "v"(hi));
    return r;
}

// block barrier with LDS-visibility only; does NOT drain vmcnt (prefetch lives)
DEVI void team_sync() {
    __builtin_amdgcn_sched_barrier(0);
    asm volatile("s_waitcnt lgkmcnt(0)" ::: "memory");
    __builtin_amdgcn_s_barrier();
    __builtin_amdgcn_sched_barrier(0);
}

// ---------------- Kernel 1: h1^T (bf16), u = exp(s1+ab1), v = exp(s2) -------
__global__ __launch_bounds__(256) void k_prep(
    const float* __restrict__ x, const float* __restrict__ W1,
    const float* __restrict__ b1, const float* __restrict__ a1,
    const float* __restrict__ ab1,
    unsigned short* __restrict__ hT1,   // [8][64][2048] bf16
    float* __restrict__ expt1,          // [8*2048]  exp(s1+ab1)
    float* __restrict__ expv)           // [8*2048]  exp(s2)
{
    __shared__ __align__(16) unsigned short hstage[64][72];
    const int tid = threadIdx.x;
    const int w = tid >> 6, lane = tid & 63;
    const int g = lane >> 4, r15 = lane & 15;
    const int blockRow = blockIdx.x * 64;
    const int rowbase = blockRow + w * 16;

    float xa[8], xb[8];
    const float* xrow = x + (long)(rowbase + r15) * 64;
#pragma unroll
    for (int e = 0; e < 8; ++e) { xa[e] = xrow[g * 8 + e]; xb[e] = xrow[32 + g * 8 + e]; }
    short8 A0 = pack8(xa), A1 = pack8(xb);

    floatx4 acc[4];
#pragma unroll
    for (int nt = 0; nt < 4; ++nt) {
        float wa[8], wb[8];
        const float* wrow = W1 + (nt * 16 + r15) * 64;
#pragma unroll
        for (int e = 0; e < 8; ++e) { wa[e] = wrow[g * 8 + e]; wb[e] = wrow[32 + g * 8 + e]; }
        short8 B0 = pack8(wa), B1 = pack8(wb);
        floatx4 c = {0.f, 0.f, 0.f, 0.f};
        c = __builtin_amdgcn_mfma_f32_16x16x32_bf16(A0, B0, c, 0, 0, 0);
        c = __builtin_amdgcn_mfma_f32_16x16x32_bf16(A1, B1, c, 0, 0, 0);
        float bias = b1[nt * 16 + r15];
#pragma unroll
        for (int q = 0; q < 4; ++q) c[q] += bias;
        acc[nt] = c;
    }

    float a1lo[4], a1hi[4];
#pragma unroll
    for (int nt = 0; nt < 4; ++nt) {
        a1lo[nt] = a1[nt * 16 + r15];
        a1hi[nt] = a1[64 + nt * 16 + r15];
    }
    float s1q[4], s2q[4];
#pragma unroll
    for (int q = 0; q < 4; ++q) {
        float s1 = 0.f, s2 = 0.f;
#pragma unroll
        for (int nt = 0; nt < 4; ++nt) { s1 += acc[nt][q] * a1lo[nt]; s2 += acc[nt][q] * a1hi[nt]; }
#pragma unroll
        for (int m = 1; m < 16; m <<= 1) { s1 += __shfl_xor(s1, m); s2 += __shfl_xor(s2, m); }
        s1q[q] = s1; s2q[q] = s2;
    }
    if (r15 == 0) {
        float abv = ab1[0];
#pragma unroll
        for (int q = 0; q < 4; ++q) {
            expt1[rowbase + 4 * g + q] = __expf(s1q[q] + abv);
            expv[rowbase + 4 * g + q]  = __expf(s2q[q]);
        }
    }

#pragma unroll
    for (int nt = 0; nt < 4; ++nt)
#pragma unroll
        for (int q = 0; q < 4; ++q)
            hstage[nt * 16 + r15][w * 16 + 4 * g + q] = f2bf(acc[nt][q]);
    __syncthreads();
    {
        const int o = tid >> 2, seg = (tid & 3) * 16;
        const int bb = blockRow >> 11;
        const int ib = blockRow & 2047;
        unsigned short* dst = hT1 + ((long)(bb * 64 + o) * 2048) + ib + seg;
        uint4 v0 = *(const uint4*)&hstage[o][seg];
        uint4 v1 = *(const uint4*)&hstage[o][seg + 8];
        *(uint4*)dst = v0;
        *(uint4*)(dst + 8) = v1;
    }
}

// ---------------- Kernel 2: masked softmax @ h1 + h2 ------------------------
// grid 256 (bb = blockIdx&7, i-tile = blockIdx>>3), block 1024 = 16 waves
// = 4 row-groups (wrow) x 4 j-teams (t). Team t owns chunks [8t, 8t+8).
__global__ __launch_bounds__(1024, 4) void k_attn(
    const float* __restrict__ x, const int* __restrict__ adj,
    const float* __restrict__ W2, const float* __restrict__ b2,
    const unsigned short* __restrict__ hT1,
    const float* __restrict__ expt1, const float* __restrict__ expv,
    float* __restrict__ out)
{
    __shared__ __align__(16) unsigned short hl[4][2][64][72];  // 73.7 KB
    __shared__ __align__(16) float vlds[2048];                 // 8 KB

    const int tid = threadIdx.x;
    const int w = tid >> 6, lane = tid & 63;
    const int t = w >> 2, wrow = w & 3;
    const int g = lane >> 4, r15 = lane & 15;
    const int bb = blockIdx.x & 7;
    const int it = blockIdx.x >> 3;
    const int rowbase = it * 64 + wrow * 16;
    const int jt0 = t * 8;

    // stage exp(s2) for the whole batch row-block once
    *(float2*)&vlds[tid * 2] = *(const float2*)&expv[bb * 2048 + tid * 2];

    const float u = expt1[bb * 2048 + rowbase + r15];   // this lane's row factor

    floatx4 acc[4];
#pragma unroll
    for (int nt = 0; nt < 4; ++nt) acc[nt] = (floatx4){0.f, 0.f, 0.f, 0.f};
    floatx4 acc5 = {0.f, 0.f, 0.f, 0.f};

    short8 ones;
#pragma unroll
    for (int i = 0; i < 8; ++i) ones[i] = (short)0x3F80;   // bf16 1.0

    const int4* adjq = (const int4*)(adj + (long)(bb * 2048 + rowbase + r15) * 2048);

    // hl staging: team-local 256 threads cover 64 f-rows x 64 j
    const int ttid = tid & 255;
    const int so = ttid >> 2, sseg = (ttid & 3) * 16;
    const unsigned short* hTsrc = hT1 + (long)(bb * 64 + so) * 2048 + sseg;
    unsigned short* hldst0 = &hl[t][0][so][sseg];
    unsigned short* hldst1 = &hl[t][1][so][sseg];

    int4 adjR[2][4];
    uint4 hrg[2][2];

#define ADJ(c) do {                                                            \
        const int base_ = (jt0 + (c)) * 16 + g * 2;                            \
        adjR[(c) & 1][0] = adjq[base_];                                        \
        adjR[(c) & 1][1] = adjq[base_ + 1];                                    \
        adjR[(c) & 1][2] = adjq[base_ + 8];                                    \
        adjR[(c) & 1][3] = adjq[base_ + 9];                                    \
    } while (0)

#define HTLOAD(c) do {                                                         \
        const unsigned short* s_ = hTsrc + (jt0 + (c)) * 64;                   \
        hrg[(c) & 1][0] = *(const uint4*)s_;                                   \
        hrg[(c) & 1][1] = *(const uint4*)(s_ + 8);                             \
    } while (0)

#define HTSTORE(c) do {                                                        \
        unsigned short* d_ = ((c) & 1) ? hldst1 : hldst0;                      \
        *(uint4*)d_ = hrg[(c) & 1][0];                                         \
        *(uint4*)(d_ + 8) = hrg[(c) & 1][1];                                   \
    } while (0)

#define COMPUTE(C) do {                                                        \
        const int vb_ = (jt0 + (C)) * 64 + g * 8;                              \
        float4 v0_ = *(const float4*)&vlds[vb_];                               \
        float4 v1_ = *(const float4*)&vlds[vb_ + 4];                           \
        float4 v2_ = *(const float4*)&vlds[vb_ + 32];                          \
        float4 v3_ = *(const float4*)&vlds[vb_ + 36];                          \
        int4 j0_ = adjR[(C) & 1][0], j1_ = adjR[(C) & 1][1];                   \
        int4 j2_ = adjR[(C) & 1][2], j3_ = adjR[(C) & 1][3];                   \
        uint4 au_, bu_;                                                        \
        au_.x = cvt_pk_bf16(j0_.x > 0 ? fmaxf(u * v0_.x, 1.f) : 0.f,           \
                            j0_.y > 0 ? fmaxf(u * v0_.y, 1.f) : 0.f);          \
        au_.y = cvt_pk_bf16(j0_.z > 0 ? fmaxf(u * v0_.z, 1.f) : 0.f,           \
                            j0_.w > 0 ? fmaxf(u * v0_.w, 1.f) : 0.f);          \
        au_.z = cvt_pk_bf16(j1_.x > 0 ? fmaxf(u * v1_.x, 1.f) : 0.f,           \
                            j1_.y > 0 ? fmaxf(u * v1_.y, 1.f) : 0.f);          \
        au_.w = cvt_pk_bf16(j1_.z > 0 ? fmaxf(u * v1_.z, 1.f) : 0.f,           \
                            j1_.w > 0 ? fmaxf(u * v1_.w, 1.f) : 0.f);          \
        bu_.x = cvt_pk_bf16(j2_.x > 0 ? fmaxf(u * v2_.x, 1.f) : 0.f,           \
                            j2_.y > 0 ? fmaxf(u * v2_.y, 1.f) : 0.f);          \
        bu_.y = cvt_pk_bf16(j2_.z > 0 ? fmaxf(u * v2_.z, 1.f) : 0.f,           \
                            j2_.w > 0 ? fmaxf(u * v2_.w, 1.f) : 0.f);          \
        bu_.z = cvt_pk_bf16(j3_.x > 0 ? fmaxf(u * v3_.x, 1.f) : 0.f,           \
                            j3_.y > 0 ? fmaxf(u * v3_.y, 1.f) : 0.f);          \
        bu_.w = cvt_pk_bf16(j3_.z > 0 ? fmaxf(u * v3_.z, 1.f) : 0.f,           \
                            j3_.w > 0 ? fmaxf(u * v3_.w, 1.f) : 0.f);          \
        short8 a0 = __builtin_bit_cast(short8, au_);                           \
        short8 a1 = __builtin_bit_cast(short8, bu_);                           \
        _Pragma("unroll")                                                      \
        for (int nt_ = 0; nt_ < 4; ++nt_) {                                    \
            short8 b0 = *(const short8*)&hl[t][(C) & 1][nt_ * 16 + r15][g * 8];      \
            short8 b1 = *(const short8*)&hl[t][(C) & 1][nt_ * 16 + r15][32 + g * 8]; \
            acc[nt_] = __builtin_amdgcn_mfma_f32_16x16x32_bf16(a0, b0, acc[nt_], 0, 0, 0); \
            acc[nt_] = __builtin_amdgcn_mfma_f32_16x16x32_bf16(a1, b1, acc[nt_], 0, 0, 0); \
        }                                                                      \
        acc5 = __builtin_amdgcn_mfma_f32_16x16x32_bf16(a0, ones, acc5, 0, 0, 0); \
        acc5 = __builtin_amdgcn_mfma_f32_16x16x32_bf16(a1, ones, acc5, 0, 0, 0); \
    } while (0)

    // prologue: adj chunks 0,1 in flight; hl[0] staged; hT chunk 1 in regs
    ADJ(0); ADJ(1);
    HTLOAD(0);
    HTSTORE(0);
    HTLOAD(1);
    team_sync();

    // NOTE: ADJ(C+2) must come AFTER COMPUTE(C) — it reuses slot adjR[C&1]
    // (WAR on the ring). Issuing it before COMPUTE was the R7 bug.
#pragma unroll
    for (int C = 0; C < 8; ++C) {
        if (C < 6) HTLOAD(C + 2);       // -> hrg[C&1] (chunk C already stored)
        if (C < 7) HTSTORE(C + 1);      // hl[(C+1)&1] <- hrg[(C+1)&1]
        COMPUTE(C);                     // reads adjR[C&1], hl[C&1]
        if (C < 6) ADJ(C + 2);          // -> adjR[C&1], after its last read
        team_sync();
    }

#undef COMPUTE
#undef HTSTORE
#undef HTLOAD
#undef ADJ

    // ---- combine 4 teams' partials (reuse hl as scratch; all computes done) ----
    float* csh = (float*)&hl[0][0][0][0];   // 12 waves x 20 x 64 f32 = 60 KB
    if (t > 0) {
        const int wb = ((t - 1) * 4 + wrow) * 20;
#pragma unroll
        for (int nt = 0; nt < 4; ++nt)
#pragma unroll
            for (int q = 0; q < 4; ++q)
                csh[(wb + nt * 4 + q) * 64 + lane] = acc[nt][q];
#pragma unroll
        for (int q = 0; q < 4; ++q)
            csh[(wb + 16 + q) * 64 + lane] = acc5[q];
    }
    __syncthreads();

    if (t == 0) {
#pragma unroll
        for (int ti = 0; ti < 3; ++ti) {
            const int wb = (ti * 4 + wrow) * 20;
#pragma unroll
            for (int nt = 0; nt < 4; ++nt)
#pragma unroll
                for (int q = 0; q < 4; ++q)
                    acc[nt][q] += csh[(wb + nt * 4 + q) * 64 + lane];
#pragma unroll
            for (int q = 0; q < 4; ++q)
                acc5[q] += csh[(wb + 16 + q) * 64 + lane];
        }
        float linv[4];
#pragma unroll
        for (int q = 0; q < 4; ++q) linv[q] = 1.0f / acc5[q];

        // h2 = x@W2^T + b2 (identity-mask layer) + store
        float xa[8], xb[8];
        const float* xrow = x + ((long)(bb * 2048 + rowbase + r15)) * 64;
#pragma unroll
        for (int e = 0; e < 8; ++e) { xa[e] = xrow[g * 8 + e]; xb[e] = xrow[32 + g * 8 + e]; }
        short8 A0 = pack8(xa), A1 = pack8(xb);
#pragma unroll
        for (int nt = 0; nt < 4; ++nt) {
            float wa[8], wb[8];
            const float* wrow2 = W2 + (nt * 16 + r15) * 64;
#pragma unroll
            for (int e = 0; e < 8; ++e) { wa[e] = wrow2[g * 8 + e]; wb[e] = wrow2[32 + g * 8 + e]; }
            short8 B0 = pack8(wa), B1 = pack8(wb);
            floatx4 c = {0.f, 0.f, 0.f, 0.f};
            c = __builtin_amdgcn_mfma_f32_16x16x32_bf16(A0, B0, c, 0, 0, 0);
            c = __builtin_amdgcn_mfma_f32_16x16x32_bf16(A1, B1, c, 0, 0, 0);
            float bias = b2[nt * 16 + r15];
#pragma unroll
            for (int q = 0; q < 4; ++q) {
                float val = acc[nt][q] * linv[q] + c[q] + bias;
                out[((long)(bb * 2048 + rowbase + 4 * g + q)) * 64 + nt * 16 + r15] = val;
            }
        }
    }
}

extern "C" void kernel_launch(void* const* d_in, const int* in_sizes, int n_in,
                              void* d_out, int out_size, void* d_ws, size_t ws_size,
                              hipStream_t stream) {
    const float* x   = (const float*)d_in[0];
    const int*   adj = (const int*)d_in[1];
    // d_in[2] identity: unused (mask == I exactly -> layer2 == h2)
    const float* W1  = (const float*)d_in[3];
    const float* b1  = (const float*)d_in[4];
    const float* a1  = (const float*)d_in[5];
    const float* ab1 = (const float*)d_in[6];
    const float* W2  = (const float*)d_in[7];
    const float* b2  = (const float*)d_in[8];
    // d_in[9] a2, d_in[10] ab2: unused

    unsigned short* hT1 = (unsigned short*)d_ws;                 // 2 MB
    float* expt1 = (float*)((char*)d_ws + (size_t)8 * 64 * 2048 * 2);
    float* expv  = expt1 + 8 * 2048;

    k_prep<<<256, 256, 0, stream>>>(x, W1, b1, a1, ab1, hT1, expt1, expv);
    k_attn<<<256, 1024, 0, stream>>>(x, adj, W2, b2, hT1, expt1, expv, (float*)d_out);
}